// Round 1
// baseline (118.952 us; speedup 1.0000x reference)
//
#include <hip/hip_runtime.h>
#include <hip/hip_bf16.h>
#include <math.h>

// Problem: B=8, N=4096 symmetric chamfer loss + trans L1.
// ws layout (bytes):
//   0      : relRot   [2][B][9]  floats (group 0 = pred, 1 = gt)   144 floats
//   576    : relTrans [2][B][3]  floats                             48 floats
//   768    : pts      [2][B][N]  float4 (x,y,z,norm2)
//   768+2*B*N*16 : rowmin [2][B][N] uint (ordered-float encoding)

#define TPB 256
#define RPT 2            // rows per thread
#define MC  512          // m-chunk staged in LDS
#define RC  (TPB * RPT)  // rows per block = 512

__device__ __forceinline__ unsigned f2ord(float f) {
    unsigned u = __float_as_uint(f);
    return (u & 0x80000000u) ? ~u : (u | 0x80000000u);
}
__device__ __forceinline__ float ord2f(unsigned u) {
    return (u & 0x80000000u) ? __uint_as_float(u & 0x7fffffffu)
                             : __uint_as_float(~u);
}

// rel_rot = Ra @ Rb^T ; rel_trans = ta - rel_rot @ tb
__global__ void k_transforms(const float* __restrict__ pred_rot,
                             const float* __restrict__ pred_trans,
                             const float* __restrict__ ctx_hyp_rot,
                             const float* __restrict__ ctx_hyp_trans,
                             const float* __restrict__ gt_rot,
                             const float* __restrict__ gt_trans,
                             const float* __restrict__ ctx_gt_rot,
                             const float* __restrict__ ctx_gt_trans,
                             float* __restrict__ relRot,
                             float* __restrict__ relTrans, int B) {
    int t = threadIdx.x;
    if (t >= 2 * B) return;
    int g = t / B, b = t % B;
    const float* Ra = (g ? gt_rot : pred_rot) + b * 9;
    const float* ta = (g ? gt_trans : pred_trans) + b * 3;
    const float* Rb = (g ? ctx_gt_rot : ctx_hyp_rot) + b * 9;
    const float* tb = (g ? ctx_gt_trans : ctx_hyp_trans) + b * 3;
    float R[9];
#pragma unroll
    for (int i = 0; i < 3; i++)
#pragma unroll
        for (int k = 0; k < 3; k++)
            R[i * 3 + k] = Ra[i * 3 + 0] * Rb[k * 3 + 0]
                         + Ra[i * 3 + 1] * Rb[k * 3 + 1]
                         + Ra[i * 3 + 2] * Rb[k * 3 + 2];
#pragma unroll
    for (int i = 0; i < 9; i++) relRot[(g * B + b) * 9 + i] = R[i];
#pragma unroll
    for (int i = 0; i < 3; i++)
        relTrans[(g * B + b) * 3 + i] =
            ta[i] - (R[i * 3 + 0] * tb[0] + R[i * 3 + 1] * tb[1] + R[i * 3 + 2] * tb[2]);
}

// pts[g][b][n] = (R p + t, ||.||^2)
__global__ void k_prep(const float* __restrict__ mp,
                       const float* __restrict__ relRot,
                       const float* __restrict__ relTrans,
                       float4* __restrict__ pts, int B, int N) {
    int idx = blockIdx.x * blockDim.x + threadIdx.x;
    if (idx >= B * N) return;
    int b = idx / N;
    float px = mp[idx * 3 + 0], py = mp[idx * 3 + 1], pz = mp[idx * 3 + 2];
#pragma unroll
    for (int g = 0; g < 2; g++) {
        const float* R = relRot + (g * B + b) * 9;
        const float* tt = relTrans + (g * B + b) * 3;
        float x = R[0] * px + R[1] * py + R[2] * pz + tt[0];
        float y = R[3] * px + R[4] * py + R[5] * pz + tt[1];
        float z = R[6] * px + R[7] * py + R[8] * pz + tt[2];
        float nrm = x * x + y * y + z * z;
        pts[(size_t)g * B * N + idx] = make_float4(x, y, z, nrm);
    }
}

// For each row r in A-chunk: min over m-chunk of (||B_m||^2 - 2 A_r.B_m),
// combined across m-chunks via ordered-uint atomicMin.
__global__ void __launch_bounds__(TPB) k_chamfer(const float4* __restrict__ pts,
                                                 unsigned* __restrict__ rowmin,
                                                 int B, int N) {
    int dir = blockIdx.z;
    int b = blockIdx.y;
    int nMC = N / MC;
    int rc = blockIdx.x / nMC;
    int mc = blockIdx.x % nMC;
    const float4* Ap = pts + ((size_t)dir * B + b) * N;
    const float4* Bp = pts + ((size_t)(1 - dir) * B + b) * N;

    __shared__ float4 sB[MC];
    int tid = threadIdx.x;
    for (int i = tid; i < MC; i += TPB) sB[i] = Bp[mc * MC + i];

    int rowBase = rc * RC;
    float4 a[RPT];
    float mn[RPT];
#pragma unroll
    for (int r = 0; r < RPT; r++) {
        a[r] = Ap[rowBase + tid + TPB * r];
        mn[r] = INFINITY;
    }
    __syncthreads();

#pragma unroll 4
    for (int m = 0; m < MC; m++) {
        float4 g = sB[m];   // wave-uniform address -> LDS broadcast
#pragma unroll
        for (int r = 0; r < RPT; r++) {
            float dot = a[r].x * g.x + a[r].y * g.y + a[r].z * g.z;
            float part = __builtin_fmaf(-2.0f, dot, g.w);  // gm^2 - 2 dot
            mn[r] = fminf(mn[r], part);
        }
    }

#pragma unroll
    for (int r = 0; r < RPT; r++) {
        size_t idx = ((size_t)dir * B + b) * N + rowBase + tid + TPB * r;
        atomicMin(&rowmin[idx], f2ord(mn[r]));
    }
}

__global__ void k_finalize(const float4* __restrict__ pts,
                           const unsigned* __restrict__ rowmin,
                           const float* __restrict__ relTrans,
                           float* __restrict__ out, int B, int N) {
    int total = 2 * B * N;
    float s = 0.0f;
    for (int i = blockIdx.x * blockDim.x + threadIdx.x; i < total;
         i += gridDim.x * blockDim.x) {
        float part = ord2f(rowmin[i]);
        float sq = fmaxf(part + pts[i].w, 0.0f);  // + ||A_row||^2, clamp
        s += sqrtf(sq);
    }
#pragma unroll
    for (int off = 32; off > 0; off >>= 1) s += __shfl_down(s, off, 64);
    __shared__ float red[TPB / 64];
    int wid = threadIdx.x >> 6, lane = threadIdx.x & 63;
    if (lane == 0) red[wid] = s;
    __syncthreads();
    if (threadIdx.x == 0) {
        float t = 0.0f;
#pragma unroll
        for (int w = 0; w < TPB / 64; w++) t += red[w];
        atomicAdd(&out[0], t / (float)(B * N));
    }
    if (blockIdx.x == 0 && threadIdx.x == 0) {
        float lt = 0.0f;
        for (int i = 0; i < 3 * B; i++)
            lt += fabsf(relTrans[i] - relTrans[3 * B + i]);
        out[1] = lt / (float)(3 * B);
    }
}

extern "C" void kernel_launch(void* const* d_in, const int* in_sizes, int n_in,
                              void* d_out, int out_size, void* d_ws, size_t ws_size,
                              hipStream_t stream) {
    const float* pred_rot      = (const float*)d_in[0];
    const float* pred_trans    = (const float*)d_in[1];
    const float* ctx_hyp_rot   = (const float*)d_in[2];
    const float* ctx_hyp_trans = (const float*)d_in[3];
    const float* gt_rot        = (const float*)d_in[4];
    const float* gt_trans      = (const float*)d_in[5];
    const float* ctx_gt_rot    = (const float*)d_in[6];
    const float* ctx_gt_trans  = (const float*)d_in[7];
    const float* model_points  = (const float*)d_in[8];

    int B = in_sizes[0] / 9;
    int N = in_sizes[8] / (3 * B);

    char* ws = (char*)d_ws;
    float*    relRot   = (float*)ws;
    float*    relTrans = (float*)(ws + 576);
    float4*   pts      = (float4*)(ws + 768);
    unsigned* rowmin   = (unsigned*)(ws + 768 + (size_t)2 * B * N * 16);
    float*    out      = (float*)d_out;

    hipMemsetAsync(rowmin, 0xFF, (size_t)2 * B * N * 4, stream);  // ordered +inf
    hipMemsetAsync(out, 0, 2 * sizeof(float), stream);

    k_transforms<<<1, 64, 0, stream>>>(pred_rot, pred_trans, ctx_hyp_rot,
                                       ctx_hyp_trans, gt_rot, gt_trans,
                                       ctx_gt_rot, ctx_gt_trans,
                                       relRot, relTrans, B);
    k_prep<<<(B * N + 255) / 256, 256, 0, stream>>>(model_points, relRot,
                                                    relTrans, pts, B, N);
    dim3 grid((N / RC) * (N / MC), B, 2);  // 64 x 8 x 2 = 1024 blocks
    k_chamfer<<<grid, TPB, 0, stream>>>(pts, rowmin, B, N);
    k_finalize<<<64, TPB, 0, stream>>>(pts, rowmin, relTrans, out, B, N);
}

// Round 2
// 98.054 us; speedup vs baseline: 1.2131x; 1.2131x over previous
//
#include <hip/hip_runtime.h>
#include <hip/hip_bf16.h>
#include <math.h>

// RelativeGeoSymLoss: B=8, N=4096 symmetric chamfer + trans L1.
// ws layout (bytes):
//   0                : pts    [2][B][N] float4 (x,y,z,||.||^2)
//   2*B*N*16         : rowmin [2][B][N] uint (ordered-float encoding)

#define TPB 256
#define RPT 8            // rows per thread -> 32 VALU insts per LDS broadcast
#define MC  128          // m-chunk staged in LDS (2 KB)
#define RC  (TPB * RPT)  // rows per block = 2048

__device__ __forceinline__ unsigned f2ord(float f) {
    unsigned u = __float_as_uint(f);
    return (u & 0x80000000u) ? ~u : (u | 0x80000000u);
}
__device__ __forceinline__ float ord2f(unsigned u) {
    return (u & 0x80000000u) ? __uint_as_float(u & 0x7fffffffu)
                             : __uint_as_float(~u);
}

// rel_rot = Ra @ Rb^T ; rel_trans = ta - rel_rot @ tb
__device__ __forceinline__ void rel_tf(const float* __restrict__ Ra,
                                       const float* __restrict__ ta,
                                       const float* __restrict__ Rb,
                                       const float* __restrict__ tb,
                                       float* R, float* t) {
#pragma unroll
    for (int i = 0; i < 3; i++)
#pragma unroll
        for (int k = 0; k < 3; k++)
            R[i * 3 + k] = Ra[i * 3 + 0] * Rb[k * 3 + 0]
                         + Ra[i * 3 + 1] * Rb[k * 3 + 1]
                         + Ra[i * 3 + 2] * Rb[k * 3 + 2];
#pragma unroll
    for (int i = 0; i < 3; i++)
        t[i] = ta[i] - (R[i * 3 + 0] * tb[0] + R[i * 3 + 1] * tb[1]
                      + R[i * 3 + 2] * tb[2]);
}

// Fused: transforms (recomputed per thread, trivial) + point transform +
// rowmin init + out init (out[0]=0, out[1]=trans L1 loss).
__global__ void k_prep(const float* __restrict__ pred_rot,
                       const float* __restrict__ pred_trans,
                       const float* __restrict__ ctx_hyp_rot,
                       const float* __restrict__ ctx_hyp_trans,
                       const float* __restrict__ gt_rot,
                       const float* __restrict__ gt_trans,
                       const float* __restrict__ ctx_gt_rot,
                       const float* __restrict__ ctx_gt_trans,
                       const float* __restrict__ mp,
                       float4* __restrict__ pts,
                       unsigned* __restrict__ rowmin,
                       float* __restrict__ out, int B, int N) {
    int idx = blockIdx.x * blockDim.x + threadIdx.x;
    if (idx >= B * N) return;
    int b = idx / N;
    float px = mp[idx * 3 + 0], py = mp[idx * 3 + 1], pz = mp[idx * 3 + 2];
    float R[9], t[3];
#pragma unroll
    for (int g = 0; g < 2; g++) {
        if (g == 0)
            rel_tf(pred_rot + b * 9, pred_trans + b * 3,
                   ctx_hyp_rot + b * 9, ctx_hyp_trans + b * 3, R, t);
        else
            rel_tf(gt_rot + b * 9, gt_trans + b * 3,
                   ctx_gt_rot + b * 9, ctx_gt_trans + b * 3, R, t);
        float x = R[0] * px + R[1] * py + R[2] * pz + t[0];
        float y = R[3] * px + R[4] * py + R[5] * pz + t[1];
        float z = R[6] * px + R[7] * py + R[8] * pz + t[2];
        pts[(size_t)g * B * N + idx] = make_float4(x, y, z, x * x + y * y + z * z);
    }
    rowmin[idx] = 0xFFFFFFFFu;
    rowmin[(size_t)B * N + idx] = 0xFFFFFFFFu;
    if (idx == 0) {
        out[0] = 0.0f;
        float lt = 0.0f;
        for (int bb = 0; bb < B; bb++) {
            float Rp[9], tp[3], Rg[9], tg[3];
            rel_tf(pred_rot + bb * 9, pred_trans + bb * 3,
                   ctx_hyp_rot + bb * 9, ctx_hyp_trans + bb * 3, Rp, tp);
            rel_tf(gt_rot + bb * 9, gt_trans + bb * 3,
                   ctx_gt_rot + bb * 9, ctx_gt_trans + bb * 3, Rg, tg);
            lt += fabsf(tp[0] - tg[0]) + fabsf(tp[1] - tg[1]) + fabsf(tp[2] - tg[2]);
        }
        out[1] = lt / (float)(3 * B);
    }
}

// Each block: RC rows x one MC-chunk of gt points. Rows pre-scaled by -2 so
// the inner pair costs 3 fma + 1 min. Cross-chunk combine via ordered atomicMin.
__global__ void __launch_bounds__(TPB) k_chamfer(const float4* __restrict__ pts,
                                                 unsigned* __restrict__ rowmin,
                                                 int B, int N) {
    int dir = blockIdx.z;
    int b = blockIdx.y;
    int nMC = N / MC;
    int rc = blockIdx.x / nMC;
    int mc = blockIdx.x % nMC;
    const float4* Ap = pts + ((size_t)dir * B + b) * N;
    const float4* Bp = pts + ((size_t)(1 - dir) * B + b) * N;

    __shared__ float4 sB[MC];
    int tid = threadIdx.x;
    for (int i = tid; i < MC; i += TPB) sB[i] = Bp[mc * MC + i];

    int rowBase = rc * RC;
    float a2x[RPT], a2y[RPT], a2z[RPT], mn[RPT];
#pragma unroll
    for (int r = 0; r < RPT; r++) {
        float4 a = Ap[rowBase + tid + TPB * r];
        a2x[r] = -2.0f * a.x;
        a2y[r] = -2.0f * a.y;
        a2z[r] = -2.0f * a.z;
        mn[r] = INFINITY;
    }
    __syncthreads();

#pragma unroll 4
    for (int m = 0; m < MC; m++) {
        float4 g = sB[m];   // wave-uniform address -> LDS broadcast
#pragma unroll
        for (int r = 0; r < RPT; r++) {
            float p = __builtin_fmaf(a2z[r], g.z, g.w);
            p = __builtin_fmaf(a2y[r], g.y, p);
            p = __builtin_fmaf(a2x[r], g.x, p);
            mn[r] = fminf(mn[r], p);
        }
    }

#pragma unroll
    for (int r = 0; r < RPT; r++) {
        size_t idx = ((size_t)dir * B + b) * N + rowBase + tid + TPB * r;
        atomicMin(&rowmin[idx], f2ord(mn[r]));
    }
}

__global__ void k_finalize(const float4* __restrict__ pts,
                           const unsigned* __restrict__ rowmin,
                           float* __restrict__ out, int B, int N) {
    int total = 2 * B * N;
    float s = 0.0f;
    for (int i = blockIdx.x * blockDim.x + threadIdx.x; i < total;
         i += gridDim.x * blockDim.x) {
        float part = ord2f(rowmin[i]);
        float sq = fmaxf(part + pts[i].w, 0.0f);  // + ||A_row||^2, clamp
        s += sqrtf(sq);
    }
#pragma unroll
    for (int off = 32; off > 0; off >>= 1) s += __shfl_down(s, off, 64);
    __shared__ float red[TPB / 64];
    int wid = threadIdx.x >> 6, lane = threadIdx.x & 63;
    if (lane == 0) red[wid] = s;
    __syncthreads();
    if (threadIdx.x == 0) {
        float t = 0.0f;
#pragma unroll
        for (int w = 0; w < TPB / 64; w++) t += red[w];
        atomicAdd(&out[0], t / (float)(B * N));
    }
}

extern "C" void kernel_launch(void* const* d_in, const int* in_sizes, int n_in,
                              void* d_out, int out_size, void* d_ws, size_t ws_size,
                              hipStream_t stream) {
    const float* pred_rot      = (const float*)d_in[0];
    const float* pred_trans    = (const float*)d_in[1];
    const float* ctx_hyp_rot   = (const float*)d_in[2];
    const float* ctx_hyp_trans = (const float*)d_in[3];
    const float* gt_rot        = (const float*)d_in[4];
    const float* gt_trans      = (const float*)d_in[5];
    const float* ctx_gt_rot    = (const float*)d_in[6];
    const float* ctx_gt_trans  = (const float*)d_in[7];
    const float* model_points  = (const float*)d_in[8];

    int B = in_sizes[0] / 9;
    int N = in_sizes[8] / (3 * B);

    char* ws = (char*)d_ws;
    float4*   pts    = (float4*)ws;
    unsigned* rowmin = (unsigned*)(ws + (size_t)2 * B * N * 16);
    float*    out    = (float*)d_out;

    k_prep<<<(B * N + TPB - 1) / TPB, TPB, 0, stream>>>(
        pred_rot, pred_trans, ctx_hyp_rot, ctx_hyp_trans,
        gt_rot, gt_trans, ctx_gt_rot, ctx_gt_trans,
        model_points, pts, rowmin, out, B, N);

    dim3 grid((N / RC) * (N / MC), B, 2);  // (2*32, 8, 2) = 1024 blocks
    k_chamfer<<<grid, TPB, 0, stream>>>(pts, rowmin, B, N);

    k_finalize<<<128, TPB, 0, stream>>>(pts, rowmin, out, B, N);
}